// Round 18
// baseline (72.442 us; speedup 1.0000x reference)
//
#include <hip/hip_runtime.h>
#include <math.h>

// LatentSDE (L=C=D=1, H=64), all nets tabulated; 4-lane groups, one
// ds_read_b128 + DPP-only cross-lane per step (R17, absmax 0.0).
// R18 isolates the remaining ~600cy/step stall with two changes:
//  (1) fallbacks OUTLINED (__noinline__) behind one expect-false branch
//      (was: ~1000s of cold inlined insts + 2 exec-mask branches/step);
//  (2) dt & sqrt(dt) prefetched in the 4-deep slots (was: per-step ts[]
//      SMEM loads sharing lgkmcnt with the ds_read -> full drains).
// Numerics/layout unchanged from R17.

#define B_SZ 8192
#define T_SZ 128
#define NBLK 128                 // scan blocks (256 thr, 64 b each)

#define NT1 1025                 // tier1 entries (z in [-128,128], dz=1/4)
#define NT2 1025                 // tier2 entries (z in [-8192,8192], dz=16)
#define NEE 1024                 // encoder pairs (x in [-8,8], dx=1/64)
#define NENT (NT1 + NT2 + NEE)

#define ENT_F 8                        // 32B entry stride
#define ZT_FLOATS (ENT_F * (NT1 + NT2))   // 16400 floats = 65.6KB
#define T2_BASEF (ENT_F * NT1)         // 8200
#define ET2G_OFF ZT_FLOATS
#define TABG_FLOATS (ZT_FLOATS + 2048) // 18448

#define NXI 1024
#define XSF 64.0f
#define XOF 512.0f

#if __has_builtin(__builtin_amdgcn_rcpf)
#define RCPF(x) __builtin_amdgcn_rcpf(x)
#else
#define RCPF(x) (1.0f / (x))
#endif
#if __has_builtin(__builtin_amdgcn_sqrtf)
#define SQRTF(x) __builtin_amdgcn_sqrtf(x)
#else
#define SQRTF(x) sqrtf(x)
#endif

__device__ __forceinline__ float sp_precise(float a) {
  return fmaxf(a, 0.0f) + log1pf(expf(-fabsf(a)));
}
__device__ __forceinline__ float wsum64(float v) {
  #pragma unroll
  for (int m = 1; m <= 32; m <<= 1) v += __shfl_xor(v, m);
  return v;
}
template <int CTRL>
__device__ __forceinline__ float dpp_mov(float v) {
  return __int_as_float(
      __builtin_amdgcn_update_dpp(0, __float_as_int(v), CTRL, 0xF, 0xF, true));
}
// quad_perm ctrls: 0xB1=[1,0,3,2] (xor1), 0x4E=[2,3,0,1] (xor2),
// 0x00 broadcast quad-lane0. R3/R16/R17-verified.

// -------- outlined cold fallbacks (rare: |z|>8192 or |c|>3) --------
__device__ __attribute__((noinline)) float f_exact_fn(
    float z, float c, const float* __restrict__ fw1,
    const float* __restrict__ fb1, const float* __restrict__ fw2, float fb2s)
{
  float s = 0.f;
  for (int j = 0; j < 64; ++j)
    s = fmaf(sp_precise(fmaf(z, fw1[j], fmaf(c, fw1[64 + j], fb1[j]))), fw2[j], s);
  return s + fb2s;
}
__device__ __attribute__((noinline)) void hgp_exact_fn(
    float z,
    const float* __restrict__ hw1, const float* __restrict__ hb1,
    const float* __restrict__ hw2, float hb2s,
    const float* __restrict__ gw1, const float* __restrict__ gb1,
    const float* __restrict__ gw2, float gb2s,
    const float* __restrict__ pw1, const float* __restrict__ pb1,
    const float* __restrict__ pw2, float pb2s,
    float* hv, float* gv, float* pv)
{
  float sh = 0.f, sg = 0.f, sp = 0.f;
  for (int j = 0; j < 64; ++j) {
    sh = fmaf(sp_precise(fmaf(z, hw1[j], hb1[j])), hw2[j], sh);
    sg = fmaf(sp_precise(fmaf(z, gw1[j], gb1[j])), gw2[j], sg);
    sp = fmaf(sp_precise(fmaf(z, pw1[j], pb1[j])), pw2[j], sp);
  }
  *hv = sh + hb2s;
  *gv = 1.0f / (1.0f + expf(-(sg + gb2s)));
  *pv = sp + pb2s;
}

// ---------------- build: one wave per entry ----------------
__global__ __launch_bounds__(256) void build_tabs(
    const float* __restrict__ ew1, const float* __restrict__ eb1,
    const float* __restrict__ ew2, const float* __restrict__ eb2,
    const float* __restrict__ fw1, const float* __restrict__ fb1,
    const float* __restrict__ fw2, const float* __restrict__ fb2,
    const float* __restrict__ hw1, const float* __restrict__ hb1,
    const float* __restrict__ hw2, const float* __restrict__ hb2,
    const float* __restrict__ gw1, const float* __restrict__ gb1,
    const float* __restrict__ gw2, const float* __restrict__ gb2,
    const float* __restrict__ pw1, const float* __restrict__ pb1,
    const float* __restrict__ pw2, const float* __restrict__ pb2,
    float* __restrict__ tabs, int* __restrict__ ctr)
{
  const int gtid = blockIdx.x * 256 + threadIdx.x;
  if (gtid == 0) *ctr = 0;
  const int ent  = gtid >> 6;
  const int lane = threadIdx.x & 63;
  if (ent >= NENT) return;

  if (ent < NT1 + NT2) {
    const bool t1 = ent < NT1;
    const int  i  = t1 ? ent : (ent - NT1);
    const float z = t1 ? (-128.0f + (float)i * 0.25f)
                       : (-8192.0f + (float)i * 16.0f);
    const int basef = (t1 ? 0 : T2_BASEF) + ENT_F * i;

    const float az = fmaf(z, fw1[lane], fb1[lane]);
    const float wc = fw1[64 + lane], w2 = fw2[lane];
    float s0 = sp_precise(fmaf(-3.0f, wc, az)) * w2;
    float s1 = sp_precise(fmaf(-1.0f, wc, az)) * w2;
    float s2 = sp_precise(fmaf( 1.0f, wc, az)) * w2;
    float s3 = sp_precise(fmaf( 3.0f, wc, az)) * w2;
    float sh = sp_precise(fmaf(z, hw1[lane], hb1[lane])) * hw2[lane];
    float sg = sp_precise(fmaf(z, gw1[lane], gb1[lane])) * gw2[lane];
    float sp = sp_precise(fmaf(z, pw1[lane], pb1[lane])) * pw2[lane];
    s0 = wsum64(s0); s1 = wsum64(s1); s2 = wsum64(s2); s3 = wsum64(s3);
    sh = wsum64(sh); sg = wsum64(sg); sp = wsum64(sp);
    if (lane == 0) {
      const float fb = fb2[0];
      tabs[basef + 0] = s0 + fb;
      tabs[basef + 1] = s1 + fb;
      tabs[basef + 2] = s2 + fb;
      tabs[basef + 3] = s3 + fb;
      tabs[basef + 4] = sh + hb2[0];
      tabs[basef + 5] = 1.0f / (1.0f + expf(-(sg + gb2[0])));
      tabs[basef + 6] = sp + pb2[0];
      tabs[basef + 7] = 0.0f;
    }
  } else {
    const int i = ent - (NT1 + NT2);
    const float x0 = -8.0f + (float)i * (1.0f / 64.0f);
    const float x1 = x0 + (1.0f / 64.0f);
    const float w = ew1[lane], bb = eb1[lane], w2 = ew2[lane];
    float s0 = sp_precise(fmaf(x0, w, bb)) * w2;
    float s1 = sp_precise(fmaf(x1, w, bb)) * w2;
    s0 = wsum64(s0); s1 = wsum64(s1);
    if (lane == 0) {
      const float eb = eb2[0];
      ((float2*)(tabs + ET2G_OFF))[i] = make_float2(s0 + eb, s1 + eb);
    }
  }
}

// ---------------- pre-pass: ctx[t,b] = enc(xs[t,b]) ----------------
__global__ __launch_bounds__(256) void ctx_pre(
    const float* __restrict__ xs, const float* __restrict__ tabs,
    float* __restrict__ ctx)
{
  const int i = blockIdx.x * 256 + threadIdx.x;
  const float2* et2 = (const float2*)(tabs + ET2G_OFF);
  const float s = fmaf(xs[i], XSF, XOF);
  const float sc = fminf(fmaxf(s, 0.0f), (float)(NXI - 1));
  const int ii = (int)sc;
  const float fr = s - (float)ii;
  const float2 e = et2[ii];
  ctx[i] = fmaf(fr, e.y - e.x, e.x);
}

// ---------------- scan: 4-lane groups, 16 b/wave ----------------
__global__ __launch_bounds__(256) void sde_scan(
    const float* __restrict__ xs, const float* __restrict__ ts,
    const float* __restrict__ noise_std, const float* __restrict__ eps0,
    const float* __restrict__ dW, const float* __restrict__ ctx,
    const float* __restrict__ qw,  const float* __restrict__ qb,
    const float* __restrict__ fw1, const float* __restrict__ fb1,
    const float* __restrict__ fw2, const float* __restrict__ fb2,
    const float* __restrict__ hw1, const float* __restrict__ hb1,
    const float* __restrict__ hw2, const float* __restrict__ hb2,
    const float* __restrict__ gw1, const float* __restrict__ gb1,
    const float* __restrict__ gw2, const float* __restrict__ gb2,
    const float* __restrict__ pw1, const float* __restrict__ pb1,
    const float* __restrict__ pw2, const float* __restrict__ pb2,
    const float* __restrict__ pz0_mean, const float* __restrict__ pz0_logstd,
    const float* __restrict__ tabsrc,
    int* __restrict__ ctr, float* __restrict__ partA, float* __restrict__ partB,
    float* __restrict__ out)
{
  __shared__ __align__(16) float tab[ZT_FLOATS];
  __shared__ float la[256], lb[256];
  __shared__ int lastflag;

  const int tid  = threadIdx.x;
  const int part = tid & 3;                 // lane within 4-lane group
  const int b    = blockIdx.x * 64 + (tid >> 2);

  { // stage z-table (4100 float4)
    const float4* s4 = (const float4*)tabsrc;
    float4* d4 = (float4*)tab;
    for (int i = tid; i < ZT_FLOATS / 4; i += 256) d4[i] = s4[i];
  }
  __syncthreads();

  const float fb2s = fb2[0], hb2s = hb2[0], gb2s = gb2[0], pb2s = pb2[0];
  const float qw0 = qw[0], qw1 = qw[1], qb0 = qb[0], qb1 = qb[1];
  const float ns = noise_std[0];
  const float inv_ns = 1.0f / ns;
  const float nh_i2 = -0.5f * inv_ns * inv_ns;
  const float pm = pz0_mean[0], pls = pz0_logstd[0];

  // two-tier index -> float base of entry fi; lane reads float4 at base+4*part
  auto zidx = [&](float z_, int& basef_, float& frac_, bool& inr_) {
    const float s1 = fmaf(z_, 4.0f, 512.0f);        // tier1 (dz=1/4)
    const float s2v = fmaf(z_, 0.0625f, 512.0f);    // tier2 (dz=16)
    const bool t1 = (s1 >= 0.0f) && (s1 <= 1024.0f);
    const bool t2 = (s2v >= 0.0f) && (s2v <= 1024.0f);
    inr_ = t1 || t2;
    const float sf = t1 ? s1 : fminf(fmaxf(s2v, 0.0f), 1024.0f);
    const int fi = min((int)sf, 1023);
    basef_ = (t1 ? 0 : T2_BASEF) + ENT_F * fi;
    frac_ = sf - (float)fi;
  };

  // ---- prologue (4 lanes redundant per b) ----
  const float c0v = ctx[b];
  const float qm  = fmaf(c0v, qw0, qb0);
  const float qls = fmaf(c0v, qw1, qb1);
  float z = fmaf(__expf(qls), eps0[b], qm);
  const float dqm = qm - pm;
  const float kl = (pls - qls)
                 + (__expf(2.0f * qls) + dqm * dqm) * (0.5f * __expf(-2.0f * pls))
                 - 0.5f;

  // 4-deep prefetch: slot j holds {xs,ctx,dW,dt,sqrt(dt)}[k=j]
  float xbuf0 = xs[0 * B_SZ + b], cbuf0 = ctx[0 * B_SZ + b], wbuf0 = dW[0 * B_SZ + b];
  float xbuf1 = xs[1 * B_SZ + b], cbuf1 = ctx[1 * B_SZ + b], wbuf1 = dW[1 * B_SZ + b];
  float xbuf2 = xs[2 * B_SZ + b], cbuf2 = ctx[2 * B_SZ + b], wbuf2 = dW[2 * B_SZ + b];
  float xbuf3 = xs[3 * B_SZ + b], cbuf3 = ctx[3 * B_SZ + b], wbuf3 = dW[3 * B_SZ + b];
  float dbuf0 = ts[1] - ts[0], dbuf1 = ts[2] - ts[1];
  float dbuf2 = ts[3] - ts[2], dbuf3 = ts[4] - ts[3];
  float qbuf0 = SQRTF(dbuf0), qbuf1 = SQRTF(dbuf1);
  float qbuf2 = SQRTF(dbuf2), qbuf3 = SQRTF(dbuf3);

  bool zin; int zb; float zfr;
  zidx(z, zb, zfr, zin);

  float lrs = 0.0f, lps = 0.0f;
  const int loff = 4 * part;     // lane's float4 within the 64B entry-pair

#define STEP(K, J) { \
    const float dt = dbuf##J; \
    const float sq = qbuf##J; \
    const float cc = cbuf##J; \
    const float c2 = cc * cc; \
    const float p1c = c2 - 1.0f, p3c = c2 - 9.0f; \
    const float L0 = p1c * (cc - 3.0f) * (-1.0f / 48.0f); \
    const float L1 = p3c * (cc - 1.0f) * ( 1.0f / 16.0f); \
    const float L2 = p3c * (cc + 1.0f) * (-1.0f / 16.0f); \
    const float L3 = p1c * (cc + 3.0f) * ( 1.0f / 48.0f); \
    const bool cin = fabsf(cc) <= 3.0f; \
    const float4 va = *(const float4*)(tab + zb + loff); \
    const float wz = (part < 2) ? (1.0f - zfr) : zfr; \
    const float dotL = fmaf(L3, va.w, fmaf(L2, va.z, fmaf(L1, va.y, L0 * va.x))); \
    float sF = wz * dotL; \
    float sG = wz * va.y; \
    float sH = wz * va.x; \
    float sP = wz * va.z; \
    sF += dpp_mov<0x4E>(sF); \
    sG += dpp_mov<0x4E>(sG); \
    sH += dpp_mov<0x4E>(sH); \
    sP += dpp_mov<0x4E>(sP); \
    float FV = sF; \
    float GV = dpp_mov<0xB1>(sG); \
    float HV = dpp_mov<0xB1>(sH); \
    float PV = sP; \
    if (__builtin_expect(!(zin && cin), 0)) { \
      FV = f_exact_fn(z, cc, fw1, fb1, fw2, fb2s); \
      if (!zin) hgp_exact_fn(z, hw1, hb1, hw2, hb2s, gw1, gb1, gw2, gb2s, \
                             pw1, pb1, pw2, pb2s, &HV, &GV, &PV); \
    } \
    const float gvs = fmaxf(GV, 1e-6f); \
    const float uu = (FV - HV) * RCPF(gvs); \
    lrs = fmaf((0.5f * dt) * uu, uu, lrs); \
    const float d_ = xbuf##J - PV; \
    lps = fmaf(nh_i2 * d_, d_, lps); \
    const float zn = fmaf(gvs * wbuf##J, sq, fmaf(FV, dt, z)); \
    z = dpp_mov<0x00>(zn); \
    /* refill slot J for step K+4 */ \
    const int kk_ = (K) + 4; \
    const int kks_ = min(kk_, T_SZ - 1); \
    const int ixc_ = kks_ * B_SZ + b; \
    const float xb_n = xs[ixc_]; \
    const float cb_n = ctx[ixc_]; \
    const float wb_n = (kk_ < T_SZ - 1) ? dW[kk_ * B_SZ + b] : 0.0f; \
    const float dt_n = ts[min(kks_ + 1, T_SZ - 1)] - ts[kks_]; \
    zidx(z, zb, zfr, zin); \
    xbuf##J = xb_n; cbuf##J = cb_n; wbuf##J = wb_n; \
    dbuf##J = dt_n; qbuf##J = SQRTF(dt_n); \
  }

  // ---- 128 iterations (k=127: dt=0, dW=0 -> lp only) ----
  for (int k = 0; k < T_SZ; k += 4) {
    STEP(k, 0); STEP(k + 1, 1); STEP(k + 2, 2); STEP(k + 3, 3);
  }
#undef STEP

  // ---- fused deterministic reduction ----
  la[tid] = (part == 1) ? lps : 0.0f;
  lb[tid] = (part == 0) ? (kl + lrs) : 0.0f;
  __syncthreads();
  for (int s = 128; s > 0; s >>= 1) {
    if (tid < s) { la[tid] += la[tid + s]; lb[tid] += lb[tid + s]; }
    __syncthreads();
  }
  if (tid == 0) {
    partA[blockIdx.x] = la[0]; partB[blockIdx.x] = lb[0];
    __threadfence();
    lastflag = (atomicAdd(ctr, 1) == NBLK - 1) ? 1 : 0;
  }
  __syncthreads();
  if (lastflag) {
    __threadfence();
    la[tid] = (tid < NBLK) ? partA[tid] : 0.0f;
    lb[tid] = (tid < NBLK) ? partB[tid] : 0.0f;
    __syncthreads();
    for (int s = 128; s > 0; s >>= 1) {
      if (tid < s) { la[tid] += la[tid + s]; lb[tid] += lb[tid + s]; }
      __syncthreads();
    }
    if (tid == 0) {
      out[0] = la[0] / (float)B_SZ
             + (float)T_SZ * (-__logf(ns) - 0.9189385332046727f);
      out[1] = lb[0] / (float)B_SZ;
    }
  }
}

extern "C" void kernel_launch(void* const* d_in, const int* in_sizes, int n_in,
                              void* d_out, int out_size, void* d_ws, size_t ws_size,
                              hipStream_t stream) {
  const float* xs        = (const float*)d_in[0];
  const float* ts        = (const float*)d_in[1];
  const float* noise_std = (const float*)d_in[2];
  const float* eps0      = (const float*)d_in[3];
  const float* dW        = (const float*)d_in[4];
  const float* ew1 = (const float*)d_in[5];
  const float* eb1 = (const float*)d_in[6];
  const float* ew2 = (const float*)d_in[7];
  const float* eb2 = (const float*)d_in[8];
  const float* qw  = (const float*)d_in[9];
  const float* qb  = (const float*)d_in[10];
  const float* fw1 = (const float*)d_in[11];
  const float* fb1 = (const float*)d_in[12];
  const float* fw2 = (const float*)d_in[13];
  const float* fb2 = (const float*)d_in[14];
  const float* hw1 = (const float*)d_in[15];
  const float* hb1 = (const float*)d_in[16];
  const float* hw2 = (const float*)d_in[17];
  const float* hb2 = (const float*)d_in[18];
  const float* gw1 = (const float*)d_in[19];
  const float* gb1 = (const float*)d_in[20];
  const float* gw2 = (const float*)d_in[21];
  const float* gb2 = (const float*)d_in[22];
  const float* pw1 = (const float*)d_in[23];
  const float* pb1 = (const float*)d_in[24];
  const float* pw2 = (const float*)d_in[25];
  const float* pb2 = (const float*)d_in[26];
  const float* pz0_mean   = (const float*)d_in[27];
  const float* pz0_logstd = (const float*)d_in[28];
  float* out = (float*)d_out;

  float* tabs  = (float*)d_ws;                       // [TABG_FLOATS]
  int*   ctr   = (int*)(tabs + TABG_FLOATS);         // [1] (+pad)
  float* partA = tabs + TABG_FLOATS + 4;             // [NBLK]
  float* partB = partA + NBLK;                       // [NBLK]
  float* ctxb  = partB + NBLK;                       // [T*B]

  build_tabs<<<(NENT * 64 + 255) / 256, 256, 0, stream>>>(
      ew1, eb1, ew2, eb2, fw1, fb1, fw2, fb2,
      hw1, hb1, hw2, hb2, gw1, gb1, gw2, gb2,
      pw1, pb1, pw2, pb2, tabs, ctr);

  ctx_pre<<<(T_SZ * B_SZ) / 256, 256, 0, stream>>>(xs, tabs, ctxb);

  sde_scan<<<NBLK, 256, 0, stream>>>(
      xs, ts, noise_std, eps0, dW, ctxb, qw, qb,
      fw1, fb1, fw2, fb2, hw1, hb1, hw2, hb2,
      gw1, gb1, gw2, gb2, pw1, pb1, pw2, pb2,
      pz0_mean, pz0_logstd, tabs, ctr, partA, partB, out);
}

// Round 19
// 60.222 us; speedup vs baseline: 1.2029x; 1.2029x over previous
//
#include <hip/hip_runtime.h>
#include <math.h>

// LatentSDE (L=C=D=1, H=64), all nets tabulated; 4-lane groups, one
// ds_read_b128 + DPP-only cross-lane per step (R17 structure, absmax 0.0).
// R18 regressed via __noinline__ fallback calls -> ABI spills (WRITE_SIZE
// 12KB -> 800KB). R19 = R17 EXACTLY (inline fallbacks, no spills) + ONLY
// the dt/sqrt(dt) 4-deep prefetch: removes per-step ts[] SMEM loads whose
// lgkmcnt waits entangle with the chain's ds_read (out-of-order SMEM ->
// full drains). Clean single-variable test of the SMEM theory.

#define B_SZ 8192
#define T_SZ 128
#define NBLK 128                 // scan blocks (256 thr, 64 b each)

#define NT1 1025                 // tier1 entries (z in [-128,128], dz=1/4)
#define NT2 1025                 // tier2 entries (z in [-8192,8192], dz=16)
#define NEE 1024                 // encoder pairs (x in [-8,8], dx=1/64)
#define NENT (NT1 + NT2 + NEE)

#define ENT_F 8                        // 32B entry stride
#define ZT_FLOATS (ENT_F * (NT1 + NT2))   // 16400 floats = 65.6KB
#define T2_BASEF (ENT_F * NT1)         // 8200
#define ET2G_OFF ZT_FLOATS
#define TABG_FLOATS (ZT_FLOATS + 2048) // 18448

#define NXI 1024
#define XSF 64.0f
#define XOF 512.0f

#if __has_builtin(__builtin_amdgcn_rcpf)
#define RCPF(x) __builtin_amdgcn_rcpf(x)
#else
#define RCPF(x) (1.0f / (x))
#endif
#if __has_builtin(__builtin_amdgcn_sqrtf)
#define SQRTF(x) __builtin_amdgcn_sqrtf(x)
#else
#define SQRTF(x) sqrtf(x)
#endif

__device__ __forceinline__ float sp_precise(float a) {
  return fmaxf(a, 0.0f) + log1pf(expf(-fabsf(a)));
}
__device__ __forceinline__ float wsum64(float v) {
  #pragma unroll
  for (int m = 1; m <= 32; m <<= 1) v += __shfl_xor(v, m);
  return v;
}
template <int CTRL>
__device__ __forceinline__ float dpp_mov(float v) {
  return __int_as_float(
      __builtin_amdgcn_update_dpp(0, __float_as_int(v), CTRL, 0xF, 0xF, true));
}
// quad_perm ctrls: 0xB1=[1,0,3,2] (xor1), 0x4E=[2,3,0,1] (xor2),
// 0x00 broadcast quad-lane0. R3/R16/R17-verified.

// ---------------- build: one wave per entry ----------------
__global__ __launch_bounds__(256) void build_tabs(
    const float* __restrict__ ew1, const float* __restrict__ eb1,
    const float* __restrict__ ew2, const float* __restrict__ eb2,
    const float* __restrict__ fw1, const float* __restrict__ fb1,
    const float* __restrict__ fw2, const float* __restrict__ fb2,
    const float* __restrict__ hw1, const float* __restrict__ hb1,
    const float* __restrict__ hw2, const float* __restrict__ hb2,
    const float* __restrict__ gw1, const float* __restrict__ gb1,
    const float* __restrict__ gw2, const float* __restrict__ gb2,
    const float* __restrict__ pw1, const float* __restrict__ pb1,
    const float* __restrict__ pw2, const float* __restrict__ pb2,
    float* __restrict__ tabs, int* __restrict__ ctr)
{
  const int gtid = blockIdx.x * 256 + threadIdx.x;
  if (gtid == 0) *ctr = 0;
  const int ent  = gtid >> 6;
  const int lane = threadIdx.x & 63;
  if (ent >= NENT) return;

  if (ent < NT1 + NT2) {
    const bool t1 = ent < NT1;
    const int  i  = t1 ? ent : (ent - NT1);
    const float z = t1 ? (-128.0f + (float)i * 0.25f)
                       : (-8192.0f + (float)i * 16.0f);
    const int basef = (t1 ? 0 : T2_BASEF) + ENT_F * i;

    const float az = fmaf(z, fw1[lane], fb1[lane]);
    const float wc = fw1[64 + lane], w2 = fw2[lane];
    float s0 = sp_precise(fmaf(-3.0f, wc, az)) * w2;
    float s1 = sp_precise(fmaf(-1.0f, wc, az)) * w2;
    float s2 = sp_precise(fmaf( 1.0f, wc, az)) * w2;
    float s3 = sp_precise(fmaf( 3.0f, wc, az)) * w2;
    float sh = sp_precise(fmaf(z, hw1[lane], hb1[lane])) * hw2[lane];
    float sg = sp_precise(fmaf(z, gw1[lane], gb1[lane])) * gw2[lane];
    float sp = sp_precise(fmaf(z, pw1[lane], pb1[lane])) * pw2[lane];
    s0 = wsum64(s0); s1 = wsum64(s1); s2 = wsum64(s2); s3 = wsum64(s3);
    sh = wsum64(sh); sg = wsum64(sg); sp = wsum64(sp);
    if (lane == 0) {
      const float fb = fb2[0];
      tabs[basef + 0] = s0 + fb;
      tabs[basef + 1] = s1 + fb;
      tabs[basef + 2] = s2 + fb;
      tabs[basef + 3] = s3 + fb;
      tabs[basef + 4] = sh + hb2[0];
      tabs[basef + 5] = 1.0f / (1.0f + expf(-(sg + gb2[0])));
      tabs[basef + 6] = sp + pb2[0];
      tabs[basef + 7] = 0.0f;
    }
  } else {
    const int i = ent - (NT1 + NT2);
    const float x0 = -8.0f + (float)i * (1.0f / 64.0f);
    const float x1 = x0 + (1.0f / 64.0f);
    const float w = ew1[lane], bb = eb1[lane], w2 = ew2[lane];
    float s0 = sp_precise(fmaf(x0, w, bb)) * w2;
    float s1 = sp_precise(fmaf(x1, w, bb)) * w2;
    s0 = wsum64(s0); s1 = wsum64(s1);
    if (lane == 0) {
      const float eb = eb2[0];
      ((float2*)(tabs + ET2G_OFF))[i] = make_float2(s0 + eb, s1 + eb);
    }
  }
}

// ---------------- pre-pass: ctx[t,b] = enc(xs[t,b]) ----------------
__global__ __launch_bounds__(256) void ctx_pre(
    const float* __restrict__ xs, const float* __restrict__ tabs,
    float* __restrict__ ctx)
{
  const int i = blockIdx.x * 256 + threadIdx.x;
  const float2* et2 = (const float2*)(tabs + ET2G_OFF);
  const float s = fmaf(xs[i], XSF, XOF);
  const float sc = fminf(fmaxf(s, 0.0f), (float)(NXI - 1));
  const int ii = (int)sc;
  const float fr = s - (float)ii;
  const float2 e = et2[ii];
  ctx[i] = fmaf(fr, e.y - e.x, e.x);
}

// ---------------- scan: 4-lane groups, 16 b/wave ----------------
__global__ __launch_bounds__(256) void sde_scan(
    const float* __restrict__ xs, const float* __restrict__ ts,
    const float* __restrict__ noise_std, const float* __restrict__ eps0,
    const float* __restrict__ dW, const float* __restrict__ ctx,
    const float* __restrict__ qw,  const float* __restrict__ qb,
    const float* __restrict__ fw1, const float* __restrict__ fb1,
    const float* __restrict__ fw2, const float* __restrict__ fb2,
    const float* __restrict__ hw1, const float* __restrict__ hb1,
    const float* __restrict__ hw2, const float* __restrict__ hb2,
    const float* __restrict__ gw1, const float* __restrict__ gb1,
    const float* __restrict__ gw2, const float* __restrict__ gb2,
    const float* __restrict__ pw1, const float* __restrict__ pb1,
    const float* __restrict__ pw2, const float* __restrict__ pb2,
    const float* __restrict__ pz0_mean, const float* __restrict__ pz0_logstd,
    const float* __restrict__ tabsrc,
    int* __restrict__ ctr, float* __restrict__ partA, float* __restrict__ partB,
    float* __restrict__ out)
{
  __shared__ __align__(16) float tab[ZT_FLOATS];
  __shared__ float la[256], lb[256];
  __shared__ int lastflag;

  const int tid  = threadIdx.x;
  const int part = tid & 3;                 // lane within 4-lane group
  const int b    = blockIdx.x * 64 + (tid >> 2);

  { // stage z-table (4100 float4)
    const float4* s4 = (const float4*)tabsrc;
    float4* d4 = (float4*)tab;
    for (int i = tid; i < ZT_FLOATS / 4; i += 256) d4[i] = s4[i];
  }
  __syncthreads();

  const float fb2s = fb2[0], hb2s = hb2[0], gb2s = gb2[0], pb2s = pb2[0];
  const float qw0 = qw[0], qw1 = qw[1], qb0 = qb[0], qb1 = qb[1];
  const float ns = noise_std[0];
  const float inv_ns = 1.0f / ns;
  const float nh_i2 = -0.5f * inv_ns * inv_ns;
  const float pm = pz0_mean[0], pls = pz0_logstd[0];

  auto hgp_exact = [&](float z_, float& hv_, float& gv_, float& pv_) {
    float sh = 0.f, sg = 0.f, sp = 0.f;
    for (int j = 0; j < 64; ++j) {
      sh = fmaf(sp_precise(fmaf(z_, hw1[j], hb1[j])), hw2[j], sh);
      sg = fmaf(sp_precise(fmaf(z_, gw1[j], gb1[j])), gw2[j], sg);
      sp = fmaf(sp_precise(fmaf(z_, pw1[j], pb1[j])), pw2[j], sp);
    }
    hv_ = sh + hb2s;
    gv_ = 1.0f / (1.0f + expf(-(sg + gb2s)));
    pv_ = sp + pb2s;
  };
  auto f_exact = [&](float z_, float c_) {
    float s = 0.f;
    for (int j = 0; j < 64; ++j)
      s = fmaf(sp_precise(fmaf(z_, fw1[j], fmaf(c_, fw1[64 + j], fb1[j]))), fw2[j], s);
    return s + fb2s;
  };
  // two-tier index -> float base of entry fi; lane reads float4 at base+4*part
  auto zidx = [&](float z_, int& basef_, float& frac_, bool& inr_) {
    const float s1 = fmaf(z_, 4.0f, 512.0f);        // tier1 (dz=1/4)
    const float s2v = fmaf(z_, 0.0625f, 512.0f);    // tier2 (dz=16)
    const bool t1 = (s1 >= 0.0f) && (s1 <= 1024.0f);
    const bool t2 = (s2v >= 0.0f) && (s2v <= 1024.0f);
    inr_ = t1 || t2;
    const float sf = t1 ? s1 : fminf(fmaxf(s2v, 0.0f), 1024.0f);
    const int fi = min((int)sf, 1023);
    basef_ = (t1 ? 0 : T2_BASEF) + ENT_F * fi;
    frac_ = sf - (float)fi;
  };

  // ---- prologue (4 lanes redundant per b) ----
  const float c0v = ctx[b];
  const float qm  = fmaf(c0v, qw0, qb0);
  const float qls = fmaf(c0v, qw1, qb1);
  float z = fmaf(__expf(qls), eps0[b], qm);
  const float dqm = qm - pm;
  const float kl = (pls - qls)
                 + (__expf(2.0f * qls) + dqm * dqm) * (0.5f * __expf(-2.0f * pls))
                 - 0.5f;

  // 4-deep prefetch: slot j holds {xs,ctx,dW,dt,sqrt(dt)}[k=j]
  float xbuf0 = xs[0 * B_SZ + b], cbuf0 = ctx[0 * B_SZ + b], wbuf0 = dW[0 * B_SZ + b];
  float xbuf1 = xs[1 * B_SZ + b], cbuf1 = ctx[1 * B_SZ + b], wbuf1 = dW[1 * B_SZ + b];
  float xbuf2 = xs[2 * B_SZ + b], cbuf2 = ctx[2 * B_SZ + b], wbuf2 = dW[2 * B_SZ + b];
  float xbuf3 = xs[3 * B_SZ + b], cbuf3 = ctx[3 * B_SZ + b], wbuf3 = dW[3 * B_SZ + b];
  float dbuf0 = ts[1] - ts[0], dbuf1 = ts[2] - ts[1];
  float dbuf2 = ts[3] - ts[2], dbuf3 = ts[4] - ts[3];
  float qbuf0 = SQRTF(dbuf0), qbuf1 = SQRTF(dbuf1);
  float qbuf2 = SQRTF(dbuf2), qbuf3 = SQRTF(dbuf3);

  bool zin; int zb; float zfr;
  zidx(z, zb, zfr, zin);

  float lrs = 0.0f, lps = 0.0f;
  const int loff = 4 * part;     // lane's float4 within the 64B entry-pair

#define STEP(K, J) { \
    const float dt = dbuf##J; \
    const float sq = qbuf##J; \
    const float cc = cbuf##J; \
    const float c2 = cc * cc; \
    const float p1c = c2 - 1.0f, p3c = c2 - 9.0f; \
    const float L0 = p1c * (cc - 3.0f) * (-1.0f / 48.0f); \
    const float L1 = p3c * (cc - 1.0f) * ( 1.0f / 16.0f); \
    const float L2 = p3c * (cc + 1.0f) * (-1.0f / 16.0f); \
    const float L3 = p1c * (cc + 3.0f) * ( 1.0f / 48.0f); \
    const bool cin = fabsf(cc) <= 3.0f; \
    const float4 va = *(const float4*)(tab + zb + loff); \
    const float wz = (part < 2) ? (1.0f - zfr) : zfr; \
    const float dotL = fmaf(L3, va.w, fmaf(L2, va.z, fmaf(L1, va.y, L0 * va.x))); \
    float sF = wz * dotL; \
    float sG = wz * va.y; \
    float sH = wz * va.x; \
    float sP = wz * va.z; \
    sF += dpp_mov<0x4E>(sF); \
    sG += dpp_mov<0x4E>(sG); \
    sH += dpp_mov<0x4E>(sH); \
    sP += dpp_mov<0x4E>(sP); \
    float FV = sF; \
    float GV = dpp_mov<0xB1>(sG); \
    float HV = dpp_mov<0xB1>(sH); \
    float PV = sP; \
    if (!(zin && cin)) FV = f_exact(z, cc); \
    if (!zin) { float he, ge, pe; hgp_exact(z, he, ge, pe); HV = he; GV = ge; PV = pe; } \
    const float gvs = fmaxf(GV, 1e-6f); \
    const float uu = (FV - HV) * RCPF(gvs); \
    lrs = fmaf((0.5f * dt) * uu, uu, lrs); \
    const float d_ = xbuf##J - PV; \
    lps = fmaf(nh_i2 * d_, d_, lps); \
    const float zn = fmaf(gvs * wbuf##J, sq, fmaf(FV, dt, z)); \
    z = dpp_mov<0x00>(zn); \
    /* refill slot J for step K+4 */ \
    const int kk_ = (K) + 4; \
    const int kks_ = min(kk_, T_SZ - 1); \
    const int ixc_ = kks_ * B_SZ + b; \
    const float xb_n = xs[ixc_]; \
    const float cb_n = ctx[ixc_]; \
    const float wb_n = (kk_ < T_SZ - 1) ? dW[kk_ * B_SZ + b] : 0.0f; \
    const float dt_n = ts[min(kks_ + 1, T_SZ - 1)] - ts[kks_]; \
    zidx(z, zb, zfr, zin); \
    xbuf##J = xb_n; cbuf##J = cb_n; wbuf##J = wb_n; \
    dbuf##J = dt_n; qbuf##J = SQRTF(dt_n); \
  }

  // ---- 128 iterations (k=127: dt=0, dW=0 -> lp only) ----
  for (int k = 0; k < T_SZ; k += 4) {
    STEP(k, 0); STEP(k + 1, 1); STEP(k + 2, 2); STEP(k + 3, 3);
  }
#undef STEP

  // ---- fused deterministic reduction ----
  la[tid] = (part == 1) ? lps : 0.0f;
  lb[tid] = (part == 0) ? (kl + lrs) : 0.0f;
  __syncthreads();
  for (int s = 128; s > 0; s >>= 1) {
    if (tid < s) { la[tid] += la[tid + s]; lb[tid] += lb[tid + s]; }
    __syncthreads();
  }
  if (tid == 0) {
    partA[blockIdx.x] = la[0]; partB[blockIdx.x] = lb[0];
    __threadfence();
    lastflag = (atomicAdd(ctr, 1) == NBLK - 1) ? 1 : 0;
  }
  __syncthreads();
  if (lastflag) {
    __threadfence();
    la[tid] = (tid < NBLK) ? partA[tid] : 0.0f;
    lb[tid] = (tid < NBLK) ? partB[tid] : 0.0f;
    __syncthreads();
    for (int s = 128; s > 0; s >>= 1) {
      if (tid < s) { la[tid] += la[tid + s]; lb[tid] += lb[tid + s]; }
      __syncthreads();
    }
    if (tid == 0) {
      out[0] = la[0] / (float)B_SZ
             + (float)T_SZ * (-__logf(ns) - 0.9189385332046727f);
      out[1] = lb[0] / (float)B_SZ;
    }
  }
}

extern "C" void kernel_launch(void* const* d_in, const int* in_sizes, int n_in,
                              void* d_out, int out_size, void* d_ws, size_t ws_size,
                              hipStream_t stream) {
  const float* xs        = (const float*)d_in[0];
  const float* ts        = (const float*)d_in[1];
  const float* noise_std = (const float*)d_in[2];
  const float* eps0      = (const float*)d_in[3];
  const float* dW        = (const float*)d_in[4];
  const float* ew1 = (const float*)d_in[5];
  const float* eb1 = (const float*)d_in[6];
  const float* ew2 = (const float*)d_in[7];
  const float* eb2 = (const float*)d_in[8];
  const float* qw  = (const float*)d_in[9];
  const float* qb  = (const float*)d_in[10];
  const float* fw1 = (const float*)d_in[11];
  const float* fb1 = (const float*)d_in[12];
  const float* fw2 = (const float*)d_in[13];
  const float* fb2 = (const float*)d_in[14];
  const float* hw1 = (const float*)d_in[15];
  const float* hb1 = (const float*)d_in[16];
  const float* hw2 = (const float*)d_in[17];
  const float* hb2 = (const float*)d_in[18];
  const float* gw1 = (const float*)d_in[19];
  const float* gb1 = (const float*)d_in[20];
  const float* gw2 = (const float*)d_in[21];
  const float* gb2 = (const float*)d_in[22];
  const float* pw1 = (const float*)d_in[23];
  const float* pb1 = (const float*)d_in[24];
  const float* pw2 = (const float*)d_in[25];
  const float* pb2 = (const float*)d_in[26];
  const float* pz0_mean   = (const float*)d_in[27];
  const float* pz0_logstd = (const float*)d_in[28];
  float* out = (float*)d_out;

  float* tabs  = (float*)d_ws;                       // [TABG_FLOATS]
  int*   ctr   = (int*)(tabs + TABG_FLOATS);         // [1] (+pad)
  float* partA = tabs + TABG_FLOATS + 4;             // [NBLK]
  float* partB = partA + NBLK;                       // [NBLK]
  float* ctxb  = partB + NBLK;                       // [T*B]

  build_tabs<<<(NENT * 64 + 255) / 256, 256, 0, stream>>>(
      ew1, eb1, ew2, eb2, fw1, fb1, fw2, fb2,
      hw1, hb1, hw2, hb2, gw1, gb1, gw2, gb2,
      pw1, pb1, pw2, pb2, tabs, ctr);

  ctx_pre<<<(T_SZ * B_SZ) / 256, 256, 0, stream>>>(xs, tabs, ctxb);

  sde_scan<<<NBLK, 256, 0, stream>>>(
      xs, ts, noise_std, eps0, dW, ctxb, qw, qb,
      fw1, fb1, fw2, fb2, hw1, hb1, hw2, hb2,
      gw1, gb1, gw2, gb2, pw1, pb1, pw2, pb2,
      pz0_mean, pz0_logstd, tabs, ctr, partA, partB, out);
}